// Round 3
// baseline (119.513 us; speedup 1.0000x reference)
//
#include <hip/hip_runtime.h>

#define N 128
#define DIM 8192
#define NW 16           // waves in solve block
#define TCAP 512        // per-wave LDS cost-tile capacity (floats)

// ---------------- wave-sync helpers ----------------------------------------
__device__ __forceinline__ void wave_fence() {
    __threadfence_block();
    __builtin_amdgcn_wave_barrier();
}
__device__ __forceinline__ int selI(int a, int b, int idx) {      // idx uniform
    int t = (idx & 64) ? b : a;
    return __shfl(t, idx & 63, 64);
}
__device__ __forceinline__ double selD(double a, double b, int idx) {
    double t = (idx & 64) ? b : a;
    return __shfl(t, idx & 63, 64);
}
__device__ __forceinline__ double embed_key(double v, int j) {
    long long b = __double_as_longlong(v);
    return __longlong_as_double((b & ~127LL) | (long long)j);
}

// ---------------- Stage 1: d2 partials (split-K) ----------------------------
// grid (2,2,64): 64x64 output tile, K-chunk 128 (2 iters of 64). 4x4 register
// tile per thread. A row-major in LDS (reads are lane-broadcast); B staged
// k-major so B-fragment ds_read_b128 is contiguous across the 16 tx lanes.
__global__ __launch_bounds__(256) void d2_partial(const float* __restrict__ A,
                                                  const float* __restrict__ B,
                                                  float* __restrict__ d2) {
    __shared__ float As[64][68];   // row stride 272 B (16B multiple)
    __shared__ float Bk[64][64];   // [k][col], rows 256 B
    const int tid = threadIdx.x;
    const int bi = blockIdx.x, bj = blockIdx.y, bz = blockIdx.z;
    const int tx = tid & 15, ty = tid >> 4;
    const int row0 = bi * 64, col0 = bj * 64;
    const int kbase = bz * 128;
    float acc[4][4] = {};

    for (int it = 0; it < 2; ++it) {
        const int k0 = kbase + it * 64;
        __syncthreads();
        // stage A: 64 rows x 16 float4; lane->quad contiguous (coalesced)
        #pragma unroll
        for (int s = 0; s < 4; ++s) {
            int e = tid + s * 256;
            int r = e >> 4, q = e & 15;
            *(float4*)&As[r][q * 4] = *(const float4*)&A[(row0 + r) * DIM + k0 + q * 4];
        }
        // stage B k-major: per s, block consumes one full 64B line per row
        #pragma unroll
        for (int s = 0; s < 4; ++s) {
            int r = tid & 63;
            int kq = (tid >> 6) + s * 4;
            float4 b4 = *(const float4*)&B[(col0 + r) * DIM + k0 + kq * 4];
            Bk[kq * 4 + 0][r] = b4.x;
            Bk[kq * 4 + 1][r] = b4.y;
            Bk[kq * 4 + 2][r] = b4.z;
            Bk[kq * 4 + 3][r] = b4.w;
        }
        __syncthreads();
        #pragma unroll
        for (int kk = 0; kk < 64; kk += 4) {
            float xr[4][4], yr[4][4];
            #pragma unroll
            for (int i = 0; i < 4; ++i)
                *(float4*)&xr[i][0] = *(const float4*)&As[4 * ty + i][kk];
            #pragma unroll
            for (int q = 0; q < 4; ++q)
                *(float4*)&yr[q][0] = *(const float4*)&Bk[kk + q][4 * tx];
            #pragma unroll
            for (int i = 0; i < 4; ++i)
                #pragma unroll
                for (int q = 0; q < 4; ++q) {
                    float a = xr[i][q];
                    #pragma unroll
                    for (int j = 0; j < 4; ++j) {
                        float d = a - yr[q][j];
                        acc[i][j] = fmaf(d, d, acc[i][j]);
                    }
                }
        }
    }
    #pragma unroll
    for (int i = 0; i < 4; ++i)
        #pragma unroll
        for (int j = 0; j < 4; ++j)
            atomicAdd(&d2[(row0 + 4 * ty + i) * N + col0 + 4 * tx + j], acc[i][j]);
}

// ---------------- Stage 2: decompose + per-class Hungarian ------------------
// Single block, 16 waves. Each wave runs an exact wave-synchronous (no
// __syncthreads) rectangular Hungarian on one label-class. If any cross-label
// entry is positive (decomposition invalid) -> single task over all 128x128.
__global__ __launch_bounds__(1024) void solve_kernel(float* __restrict__ gmg,
                                                     const int* __restrict__ t1,
                                                     const int* __restrict__ t2,
                                                     float* __restrict__ out) {
    __shared__ int lbl1[N], lbl2[N];
    __shared__ int rowlist[N], collist[N];
    __shared__ int rcnt[64], ccnt[64], rstart[65], cstart[65], rcur[64], ccur[64];
    __shared__ int tasks[65];
    __shared__ int ntasks_s, flag_s;
    __shared__ double totals[NW];
    __shared__ float ctile[NW][TCAP];
    __shared__ int   claimw[NW][N];

    const int tid = threadIdx.x;
    if (tid < 64) { rcnt[tid] = 0; ccnt[tid] = 0; rcur[tid] = 0; ccur[tid] = 0; }
    if (tid == 0) { ntasks_s = 0; flag_s = 0; }
    if (tid < N)  { lbl1[tid] = t1[tid]; lbl2[tid] = t2[tid]; }
    __syncthreads();
    if (tid < N) {
        int l1 = lbl1[tid], l2 = lbl2[tid];
        if (l1 < 0 || l1 > 63 || l2 < 0 || l2 > 63) atomicOr(&flag_s, 1);
        atomicAdd(&rcnt[l1 & 63], 1);
        atomicAdd(&ccnt[l2 & 63], 1);
    }
    // transform d2 -> gm in place; detect positive cross-label entries
    for (int e = tid; e < N * N; e += 1024) {
        int i = e >> 7, j = e & 127;
        float v = gmg[e];
        bool same = (lbl1[i] == lbl2[j]);
        float g = same ? fmaxf(v, 0.f) : fmaxf(200.f - v, 0.f);
        if (!same && g > 0.f) atomicOr(&flag_s, 1);
        gmg[e] = g;
    }
    __threadfence();
    __syncthreads();
    // wave-0 parallel prefix over class counts + ballot task compaction
    if (tid < 64) {
        int rs_ = rcnt[tid], cs_ = ccnt[tid];
        #pragma unroll
        for (int o = 1; o < 64; o <<= 1) {
            int tr = __shfl_up(rs_, o, 64);
            int tc = __shfl_up(cs_, o, 64);
            if (tid >= o) { rs_ += tr; cs_ += tc; }
        }
        rstart[tid + 1] = rs_;
        cstart[tid + 1] = cs_;
        if (tid == 0) { rstart[0] = 0; cstart[0] = 0; }
        if (!flag_s) {
            bool valid = (rcnt[tid] > 0) && (ccnt[tid] > 0);
            unsigned long long mask = __ballot(valid);
            if (valid) {
                int pos = __popcll(mask & ((1ull << tid) - 1));
                tasks[pos] = tid;
            }
            if (tid == 0) ntasks_s = __popcll(mask);
        } else {
            if (tid == 0) { tasks[0] = -1; ntasks_s = 1; }
        }
    }
    __syncthreads();
    if (tid < N) {       // counting-sort scatter: rows/cols grouped by label
        int l1 = lbl1[tid] & 63;
        int p = atomicAdd(&rcur[l1], 1);
        rowlist[rstart[l1] + p] = tid;
        int l2 = lbl2[tid] & 63;
        int q = atomicAdd(&ccur[l2], 1);
        collist[cstart[l2] + q] = tid;
    }
    __syncthreads();

    const int w = tid >> 6, lane = tid & 63;
    const int ntasks = ntasks_s;
    double acc = 0.0;

    for (int tk = w; tk < ntasks; tk += NW) {
        const int c = tasks[tk];
        int rs, Rn, cs, Cn;
        if (c < 0) { rs = 0; Rn = N; cs = 0; Cn = N; }
        else { rs = rstart[c]; Rn = rcnt[c]; cs = cstart[c]; Cn = ccnt[c]; }
        const int* rl = rowlist + rs;
        const int* cl = collist + cs;
        const bool T  = (Rn > Cn);          // ensure n_ <= m_
        const int n_  = T ? Cn : Rn;
        const int m_  = T ? Rn : Cn;
        const bool tile = (n_ * m_ <= TCAP);
        float* Cw = ctile[w];
        int*  clm = claimw[w];

        auto offg = [&](int j) { return T ? rl[j] * N : cl[j]; };
        auto rbg  = [&](int i) { return T ? cl[i] : rl[i] * N; };

        if (tile) {
            for (int e = lane; e < n_ * m_; e += 64) {
                int i = e / m_, j = e - i * m_;
                Cw[e] = gmg[rbg(i) + offg(j)];
            }
        }
        wave_fence();

        const float* CM = tile ? Cw : gmg;
        const int je0 = lane, je1 = lane + 64;
        const bool cA = (je0 < m_), cB = (je1 < m_);
        const bool rA = (je0 < n_), rB = (je1 < n_);
        const int off0 = cA ? (tile ? je0 : offg(je0)) : 0;
        const int off1 = cB ? (tile ? je1 : offg(je1)) : 0;
        const int rb0  = rA ? (tile ? je0 * m_ : rbg(je0)) : 0;
        const int rb1  = rB ? (tile ? je1 * m_ : rbg(je1)) : 0;

        // ---- row reduction: u[i] = -max_j gm(i,j)  (gm >= 0) ----
        double u0 = 0.0, u1 = 0.0;
        if (rA) { float mx = 0.f; for (int j = 0; j < m_; ++j) mx = fmaxf(mx, CM[rb0 + (tile ? j : offg(j))]); u0 = -(double)mx; }
        if (rB) { float mx = 0.f; for (int j = 0; j < m_; ++j) mx = fmaxf(mx, CM[rb1 + (tile ? j : offg(j))]); u1 = -(double)mx; }

        // ---- col reduction: v[j] = min_i (cost(i,j) - u[i]) ----
        double v0 = 1e30, v1 = 1e30;
        for (int i = 0; i < n_; ++i) {
            int rbI = tile ? i * m_ : selI(rb0, rb1, i);
            double ui = selD(u0, u1, i);
            if (cA) v0 = fmin(v0, -(double)CM[rbI + off0] - ui);
            if (cB) v1 = fmin(v1, -(double)CM[rbI + off1] - ui);
        }

        // ---- greedy tight assignment (claim via LDS atomicMin) ----
        if (cA) clm[je0] = 0x7fffffff;
        if (cB) clm[je1] = 0x7fffffff;
        wave_fence();
        int jc0 = -1, jc1 = -1;
        for (int j = 0; j < m_; ++j) {
            double vj = selD(v0, v1, j);
            int ofj = tile ? j : selI(off0, off1, j);
            if (rA && jc0 < 0) { double s = -(double)CM[rb0 + ofj] - u0 - vj; if (s < 1e-7) jc0 = j; }
            if (rB && jc1 < 0) { double s = -(double)CM[rb1 + ofj] - u1 - vj; if (s < 1e-7) jc1 = j; }
        }
        if (rA && jc0 >= 0) atomicMin(&clm[jc0], je0);
        if (rB && jc1 >= 0) atomicMin(&clm[jc1], je1);
        wave_fence();
        int p0 = -1, p1 = -1;                 // matched row per owned col
        if (cA && clm[je0] != 0x7fffffff) p0 = clm[je0];
        if (cB && clm[je1] != 0x7fffffff) p1 = clm[je1];
        bool mr0 = (rA && jc0 >= 0 && clm[jc0] == je0);
        bool mr1 = (rB && jc1 >= 0 && clm[jc1] == je1);

        int mx2 = (n_ > m_) ? n_ : m_;
        int grp = 1; while (grp < mx2 && grp < 64) grp <<= 1;

        // ---- augmentation phases (phase-local delta reformulation) ----
        for (int ir = 0; ir < n_; ++ir) {
            if (selI(mr0 ? 1 : 0, mr1 ? 1 : 0, ir)) continue;
            double minv0 = 1e30, minv1 = 1e30;
            bool used0 = false, used1 = false;
            int way0 = -2, way1 = -2;
            double markD0 = -1.0, markD1 = -1.0, ent0 = -1.0, ent1 = -1.0;
            if (rA && je0 == ir) ent0 = 0.0;
            if (rB && je1 == ir) ent1 = 0.0;
            double D = 0.0;
            int i0 = ir, jprev = -1;
            int guard = 2 * m_ + 8;
            while (guard-- > 0) {
                int rbI = tile ? i0 * m_ : selI(rb0, rb1, i0);
                double ui = selD(u0, u1, i0);
                double base = D - ui;
                if (cA && !used0) { double cand = base - (double)CM[rbI + off0] - v0; if (cand < minv0) { minv0 = cand; way0 = jprev; } }
                if (cB && !used1) { double cand = base - (double)CM[rbI + off1] - v1; if (cand < minv1) { minv1 = cand; way1 = jprev; } }
                double k0d = (cA && !used0) ? embed_key(minv0, je0) : 1e30;
                double k1d = (cB && !used1) ? embed_key(minv1, je1) : 1e30;
                double kd = fmin(k0d, k1d);
                for (int o = 1; o < grp; o <<= 1) kd = fmin(kd, __shfl_xor(kd, o, 64));
                if (grp < 64) kd = __shfl(kd, 0, 64);      // uniformity
                long long kb = __double_as_longlong(kd);
                int j1 = (int)(kb & 127);
                double Dn = __longlong_as_double(kb & ~127LL);
                if (Dn > 1e29) break;                      // pathological guard
                D = Dn;
                int i1 = selI(p0, p1, j1);
                if (i1 < 0) {
                    // augment along way[] chain (endpoint col never marked)
                    int jj = j1;
                    while (true) {
                        int wp = selI(way0, way1, jj);
                        int pn = (wp < 0) ? ir : selI(p0, p1, wp);
                        if (cA && je0 == jj) p0 = pn;
                        if (cB && je1 == jj) p1 = pn;
                        if (wp < 0) break;
                        jj = wp;
                    }
                    if (rA && je0 == ir) mr0 = true;
                    if (rB && je1 == ir) mr1 = true;
                    break;
                }
                if (cA && je0 == j1) { used0 = true; markD0 = D; }
                if (cB && je1 == j1) { used1 = true; markD1 = D; }
                if (rA && je0 == i1) ent0 = D;
                if (rB && je1 == i1) ent1 = D;
                jprev = j1; i0 = i1;
            }
            // finalize potentials: tree rows / used cols
            if (rA && ent0   >= 0.0) u0 += D - ent0;
            if (rB && ent1   >= 0.0) u1 += D - ent1;
            if (cA && markD0 >= 0.0) v0 -= D - markD0;
            if (cB && markD1 >= 0.0) v1 -= D - markD1;
        }

        // ---- class value: sum gm(p[j], j) over matched cols ----
        int q0 = (p0 >= 0) ? p0 : 0;
        int ra1 = __shfl(rb0, q0 & 63, 64);
        int ra2 = __shfl(rb1, q0 & 63, 64);
        double val = 0.0;
        if (cA && p0 >= 0) { int rbP = tile ? p0 * m_ : ((q0 & 64) ? ra2 : ra1); val += (double)CM[rbP + off0]; }
        int q1 = (p1 >= 0) ? p1 : 0;
        int rb1s = __shfl(rb0, q1 & 63, 64);
        int rb2s = __shfl(rb1, q1 & 63, 64);
        if (cB && p1 >= 0) { int rbP = tile ? p1 * m_ : ((q1 & 64) ? rb2s : rb1s); val += (double)CM[rbP + off1]; }
        for (int o = 1; o < 64; o <<= 1) val += __shfl_xor(val, o, 64);
        acc += val;
    }

    if (lane == 0) totals[w] = acc;
    __syncthreads();
    if (tid == 0) {
        double s = 0.0;
        for (int i = 0; i < NW; ++i) s += totals[i];
        out[0] = (float)(s / (double)N);
    }
}

extern "C" void kernel_launch(void* const* d_in, const int* in_sizes, int n_in,
                              void* d_out, int out_size, void* d_ws, size_t ws_size,
                              hipStream_t stream) {
    const float* A  = (const float*)d_in[0];
    const float* B  = (const float*)d_in[1];
    const int*   t1 = (const int*)d_in[2];
    const int*   t2 = (const int*)d_in[3];
    float* out = (float*)d_out;
    float* ws  = (float*)d_ws;                 // d2 / gm scratch: 64 KiB

    hipMemsetAsync(ws, 0, N * N * sizeof(float), stream);
    d2_partial<<<dim3(2, 2, 64), 256, 0, stream>>>(A, B, ws);
    solve_kernel<<<1, 1024, 0, stream>>>(ws, t1, t2, out);
}

// Round 4
// 115.910 us; speedup vs baseline: 1.0311x; 1.0311x over previous
//
#include <hip/hip_runtime.h>

#define N 128
#define DIM 8192
#define NW 16           // waves in solve block
#define TCAP 512        // per-wave LDS cost-tile capacity (floats)

// ---------------- wave-sync helpers ----------------------------------------
__device__ __forceinline__ void wave_fence() {
    __threadfence_block();
    __builtin_amdgcn_wave_barrier();
}
__device__ __forceinline__ double embed_key(double v, int j) {
    long long b = __double_as_longlong(v);
    return __longlong_as_double((b & ~127LL) | (long long)j);
}

// ---------------- Stage 1: d2 partials (split-K) ----------------------------
// grid (2,2,64): 64x64 tile, K-chunk 128. 4x4 register tile per thread.
__global__ __launch_bounds__(256) void d2_partial(const float* __restrict__ A,
                                                  const float* __restrict__ B,
                                                  float* __restrict__ d2) {
    __shared__ float As[64][68];
    __shared__ float Bk[64][64];   // [k][col]
    const int tid = threadIdx.x;
    const int bi = blockIdx.x, bj = blockIdx.y, bz = blockIdx.z;
    const int tx = tid & 15, ty = tid >> 4;
    const int row0 = bi * 64, col0 = bj * 64;
    const int kbase = bz * 128;
    float acc[4][4] = {};

    for (int it = 0; it < 2; ++it) {
        const int k0 = kbase + it * 64;
        __syncthreads();
        #pragma unroll
        for (int s = 0; s < 4; ++s) {
            int e = tid + s * 256;
            int r = e >> 4, q = e & 15;
            *(float4*)&As[r][q * 4] = *(const float4*)&A[(row0 + r) * DIM + k0 + q * 4];
        }
        #pragma unroll
        for (int s = 0; s < 4; ++s) {
            int r = tid & 63;
            int kq = (tid >> 6) + s * 4;
            float4 b4 = *(const float4*)&B[(col0 + r) * DIM + k0 + kq * 4];
            Bk[kq * 4 + 0][r] = b4.x;
            Bk[kq * 4 + 1][r] = b4.y;
            Bk[kq * 4 + 2][r] = b4.z;
            Bk[kq * 4 + 3][r] = b4.w;
        }
        __syncthreads();
        #pragma unroll
        for (int kk = 0; kk < 64; kk += 4) {
            float xr[4][4], yr[4][4];
            #pragma unroll
            for (int i = 0; i < 4; ++i)
                *(float4*)&xr[i][0] = *(const float4*)&As[4 * ty + i][kk];
            #pragma unroll
            for (int q = 0; q < 4; ++q)
                *(float4*)&yr[q][0] = *(const float4*)&Bk[kk + q][4 * tx];
            #pragma unroll
            for (int i = 0; i < 4; ++i)
                #pragma unroll
                for (int q = 0; q < 4; ++q) {
                    float a = xr[i][q];
                    #pragma unroll
                    for (int j = 0; j < 4; ++j) {
                        float d = a - yr[q][j];
                        acc[i][j] = fmaf(d, d, acc[i][j]);
                    }
                }
        }
    }
    #pragma unroll
    for (int i = 0; i < 4; ++i)
        #pragma unroll
        for (int j = 0; j < 4; ++j)
            atomicAdd(&d2[(row0 + 4 * ty + i) * N + col0 + 4 * tx + j], acc[i][j]);
}

// ---------------- Stage 2: decompose + per-class Hungarian ------------------
// Single-role lean wave solver (m<=64): lane L is simultaneously col L and
// row L. Classes with m>64 (or flagged inputs) go to a block-wide solver.
__global__ __launch_bounds__(1024) void solve_kernel(float* __restrict__ gmg,
                                                     const int* __restrict__ t1,
                                                     const int* __restrict__ t2,
                                                     float* __restrict__ out) {
    __shared__ int lbl1[N], lbl2[N];
    __shared__ int rowlist[N], collist[N];
    __shared__ int rcnt[64], ccnt[64], rstart[65], cstart[65], rcur[64], ccur[64];
    __shared__ int tasks[65], bigtasks[65];
    __shared__ int ntasks_s, nbig_s, flag_s;
    __shared__ double totals[NW];
    __shared__ float ctile[NW][TCAP];
    __shared__ int   claimw[NW][64];
    // block-wide (fallback) solver scratch
    __shared__ double ub[N + 1], vbp[N + 1], minvb[N + 1];
    __shared__ int pb[N + 1], wayb[N + 1], usedb[N + 1];
    __shared__ double redv[NW];
    __shared__ int redi[NW];
    __shared__ double big_total;
    __shared__ int jfin_s;

    const int tid = threadIdx.x;
    if (tid < 64) { rcnt[tid] = 0; ccnt[tid] = 0; rcur[tid] = 0; ccur[tid] = 0; }
    if (tid == 0) { ntasks_s = 0; nbig_s = 0; flag_s = 0; big_total = 0.0; }
    if (tid < N)  { lbl1[tid] = t1[tid]; lbl2[tid] = t2[tid]; }
    __syncthreads();
    if (tid < N) {
        int l1 = lbl1[tid], l2 = lbl2[tid];
        if (l1 < 0 || l1 > 63 || l2 < 0 || l2 > 63) atomicOr(&flag_s, 1);
        atomicAdd(&rcnt[l1 & 63], 1);
        atomicAdd(&ccnt[l2 & 63], 1);
    }
    // d2 -> gm in place; detect positive cross-label entries
    for (int e = tid; e < N * N; e += 1024) {
        int i = e >> 7, j = e & 127;
        float v = gmg[e];
        bool same = (lbl1[i] == lbl2[j]);
        float g = same ? fmaxf(v, 0.f) : fmaxf(200.f - v, 0.f);
        if (!same && g > 0.f) atomicOr(&flag_s, 1);
        gmg[e] = g;
    }
    __threadfence();
    __syncthreads();
    // wave-0 prefix over class counts + ballot task compaction
    if (tid < 64) {
        int rs_ = rcnt[tid], cs_ = ccnt[tid];
        #pragma unroll
        for (int o = 1; o < 64; o <<= 1) {
            int tr = __shfl_up(rs_, o, 64);
            int tc = __shfl_up(cs_, o, 64);
            if (tid >= o) { rs_ += tr; cs_ += tc; }
        }
        rstart[tid + 1] = rs_;
        cstart[tid + 1] = cs_;
        if (tid == 0) { rstart[0] = 0; cstart[0] = 0; }
        if (!flag_s) {
            int R = rcnt[tid], C = ccnt[tid];
            bool valid = (R > 0) && (C > 0);
            bool small = valid && (R <= 64) && (C <= 64);
            bool big   = valid && !small;
            unsigned long long ms = __ballot(small);
            unsigned long long mb = __ballot(big);
            if (small) tasks[__popcll(ms & ((1ull << tid) - 1))] = tid;
            if (big)   bigtasks[__popcll(mb & ((1ull << tid) - 1))] = tid;
            if (tid == 0) { ntasks_s = __popcll(ms); nbig_s = __popcll(mb); }
        } else if (tid == 0) { ntasks_s = 0; nbig_s = 1; bigtasks[0] = -1; }
    }
    __syncthreads();
    if (tid < N) {       // counting-sort scatter
        int l1 = lbl1[tid] & 63;
        int p = atomicAdd(&rcur[l1], 1);
        rowlist[rstart[l1] + p] = tid;
        int l2 = lbl2[tid] & 63;
        int q = atomicAdd(&ccur[l2], 1);
        collist[cstart[l2] + q] = tid;
    }
    __syncthreads();

    const int w = tid >> 6, lane = tid & 63;
    const int ntasks = ntasks_s;
    double acc = 0.0;

    // ================= lean wave solver (single-role lanes) =================
    for (int tk = w; tk < ntasks; tk += NW) {
        const int c = tasks[tk];
        const int Rn = rcnt[c], Cn = ccnt[c];
        const int* rl = rowlist + rstart[c];
        const int* cl = collist + cstart[c];
        const bool T  = (Rn > Cn);
        const int n_  = T ? Cn : Rn;
        const int m_  = T ? Rn : Cn;        // n_ <= m_ <= 64
        const bool tl = (n_ * m_ <= TCAP);
        float* Cw = ctile[w];
        int*  clm = claimw[w];

        auto offg = [&](int j) { return T ? rl[j] * N : cl[j]; };
        auto rbg  = [&](int i) { return T ? cl[i] : rl[i] * N; };

        if (tl) {
            for (int e = lane; e < n_ * m_; e += 64) {
                int i = e / m_, j = e - i * m_;
                Cw[e] = gmg[rbg(i) + offg(j)];
            }
        }
        wave_fence();

        const float* CM = tl ? Cw : gmg;
        const bool cA = (lane < m_), rA = (lane < n_);
        const int myoff = cA ? (tl ? lane : offg(lane)) : 0;   // col role
        const int myrb  = rA ? (tl ? lane * m_ : rbg(lane)) : 0; // row role

        // row reduction: u = -max_j gm(row=lane, j)
        double u = 0.0;
        if (rA) {
            float mx = 0.f;
            for (int j = 0; j < m_; ++j) mx = fmaxf(mx, CM[myrb + (tl ? j : offg(j))]);
            u = -(double)mx;
        }
        // col reduction: v = min_i (-gm(i, col=lane) - u_i)
        double v = 1e30;
        for (int i = 0; i < n_; ++i) {
            double ui = __shfl(u, i, 64);
            int rb = tl ? i * m_ : rbg(i);
            if (cA) v = fmin(v, -(double)CM[rb + myoff] - ui);
        }
        // greedy tight assignment
        if (cA) clm[lane] = 0x7fffffff;
        wave_fence();
        int jc = -1;
        for (int j = 0; j < m_; ++j) {
            double vj = __shfl(v, j, 64);
            int ofj = tl ? j : offg(j);
            if (rA && jc < 0) {
                double s = -(double)CM[myrb + ofj] - u - vj;
                if (s < 1e-7) jc = j;
            }
        }
        if (rA && jc >= 0) atomicMin(&clm[jc], lane);
        wave_fence();
        int p = -1;                           // col role: matched row
        if (cA && clm[lane] != 0x7fffffff) p = clm[lane];
        bool rowm = (rA && jc >= 0 && clm[jc] == lane);

        // augmentation phases
        for (int ir = 0; ir < n_; ++ir) {
            if (__shfl(rowm ? 1 : 0, ir, 64)) continue;
            double minv = 1e30, markD = -1.0, ent = -1.0;
            bool used = false; int way = -2;
            if (rA && lane == ir) ent = 0.0;
            double D = 0.0;
            int i0 = ir, jprev = -1;
            int guard = 2 * m_ + 8;
            while (guard-- > 0) {
                double ui = __shfl(u, i0, 64);
                int rb = tl ? i0 * m_ : rbg(i0);
                if (cA && !used) {
                    double cand = D - ui - (double)CM[rb + myoff] - v;
                    if (cand < minv) { minv = cand; way = jprev; }
                }
                double kd = (cA && !used) ? embed_key(minv, lane) : 1e30;
                #pragma unroll
                for (int o = 1; o < 64; o <<= 1) kd = fmin(kd, __shfl_xor(kd, o, 64));
                long long kb = __double_as_longlong(kd);
                int j1 = (int)(kb & 127);
                double Dn = __longlong_as_double(kb & ~127LL);
                if (Dn > 1e29) break;
                D = Dn;
                int i1 = __shfl(p, j1, 64);
                if (i1 < 0) {                 // free col: augment along way[]
                    int jj = j1;
                    while (true) {
                        int wp = __shfl(way, jj, 64);
                        int pn = (wp < 0) ? ir : __shfl(p, wp, 64);
                        if (cA && lane == jj) p = pn;
                        if (wp < 0) break;
                        jj = wp;
                    }
                    if (rA && lane == ir) rowm = true;
                    break;
                }
                if (cA && lane == j1) { used = true; markD = D; }
                if (rA && lane == i1) ent = D;
                jprev = j1; i0 = i1;
            }
            if (rA && ent   >= 0.0) u += D - ent;
            if (cA && markD >= 0.0) v -= D - markD;
        }

        // class value
        double val = 0.0;
        if (cA && p >= 0) {
            int rb = tl ? p * m_ : rbg(p);
            val = (double)CM[rb + myoff];
        }
        #pragma unroll
        for (int o = 1; o < 64; o <<= 1) val += __shfl_xor(val, o, 64);
        acc += val;
    }
    if (lane == 0) totals[w] = acc;
    __syncthreads();

    // ================= block-wide fallback solver (rare) ====================
    const int nbig = nbig_s;
    for (int bt = 0; bt < nbig; ++bt) {
        const int c = bigtasks[bt];
        int Rn, Cn, rs, cs;
        if (c < 0) { Rn = N; Cn = N; rs = 0; cs = 0; }
        else { Rn = rcnt[c]; Cn = ccnt[c]; rs = rstart[c]; cs = cstart[c]; }
        const bool T = (Rn > Cn);
        const int n_ = T ? Cn : Rn, m_ = T ? Rn : Cn;
        auto cost = [&](int i, int j) -> double {   // oriented 0-based
            int oi = (c < 0) ? i : (T ? collist[cs + i] : rowlist[rs + i]);
            int oj = (c < 0) ? j : (T ? rowlist[rs + j] : collist[cs + j]);
            int rr = T ? oj : oi, cc2 = T ? oi : oj;
            return -(double)gmg[rr * N + cc2];
        };
        for (int x = tid; x <= m_; x += 1024) { vbp[x] = 0.0; pb[x] = 0; }
        for (int x = tid; x <= n_; x += 1024) { ub[x] = 0.0; }
        __syncthreads();
        for (int i = 1; i <= n_; ++i) {
            if (tid == 0) pb[0] = i;
            for (int x = tid; x <= m_; x += 1024) { minvb[x] = 1e300; usedb[x] = 0; }
            __syncthreads();
            int j0 = 0;
            int guard = 2 * m_ + 8;
            while (guard-- > 0) {
                if (tid == 0) usedb[j0] = 1;
                __syncthreads();
                const int i0 = pb[j0];
                double dl = 1e300; int jl = 0;
                if (tid < m_) {
                    int j = tid + 1;
                    if (!usedb[j]) {
                        double cur = cost(i0 - 1, j - 1) - ub[i0] - vbp[j];
                        if (cur < minvb[j]) { minvb[j] = cur; wayb[j] = j0; }
                        dl = minvb[j]; jl = j;
                    }
                }
                double rv = dl; int ri = jl;
                #pragma unroll
                for (int o = 32; o > 0; o >>= 1) {
                    double ov = __shfl_down(rv, o, 64);
                    int oi2 = __shfl_down(ri, o, 64);
                    if (ov < rv) { rv = ov; ri = oi2; }
                }
                if ((tid & 63) == 0) { redv[tid >> 6] = rv; redi[tid >> 6] = ri; }
                __syncthreads();
                if (tid == 0) {
                    double bd = 1e300; int bj = 0;
                    for (int q = 0; q < NW; ++q) if (redv[q] < bd) { bd = redv[q]; bj = redi[q]; }
                    redv[0] = bd; redi[0] = bj;
                }
                __syncthreads();
                const double delta = redv[0];
                const int j1 = redi[0];
                if (tid < m_) {
                    int j = tid + 1;
                    if (usedb[j]) { ub[pb[j]] += delta; vbp[j] -= delta; }
                    else          { minvb[j] -= delta; }
                }
                if (tid == 0) ub[pb[0]] += delta;
                __syncthreads();
                j0 = j1;
                if (pb[j0] == 0) break;
            }
            if (tid == 0) jfin_s = j0;
            __syncthreads();
            if (tid == 0) {
                int jj = jfin_s;
                while (jj) { int jp = wayb[jj]; pb[jj] = pb[jp]; jj = jp; }
            }
            __syncthreads();
        }
        double bl = 0.0;
        if (tid < m_) { int j = tid + 1; if (pb[j] != 0) bl = -cost(pb[j] - 1, j - 1); }
        #pragma unroll
        for (int o = 32; o > 0; o >>= 1) bl += __shfl_down(bl, o, 64);
        if ((tid & 63) == 0) redv[tid >> 6] = bl;
        __syncthreads();
        if (tid == 0) { double s = 0; for (int q = 0; q < NW; ++q) s += redv[q]; big_total += s; }
        __syncthreads();
    }

    if (tid == 0) {
        double s = big_total;
        for (int i = 0; i < NW; ++i) s += totals[i];
        out[0] = (float)(s / (double)N);
    }
}

extern "C" void kernel_launch(void* const* d_in, const int* in_sizes, int n_in,
                              void* d_out, int out_size, void* d_ws, size_t ws_size,
                              hipStream_t stream) {
    const float* A  = (const float*)d_in[0];
    const float* B  = (const float*)d_in[1];
    const int*   t1 = (const int*)d_in[2];
    const int*   t2 = (const int*)d_in[3];
    float* out = (float*)d_out;
    float* ws  = (float*)d_ws;

    hipMemsetAsync(ws, 0, N * N * sizeof(float), stream);
    d2_partial<<<dim3(2, 2, 64), 256, 0, stream>>>(A, B, ws);
    solve_kernel<<<1, 1024, 0, stream>>>(ws, t1, t2, out);
}